// Round 12
// baseline (156.061 us; speedup 1.0000x reference)
//
#include <hip/hip_runtime.h>

#define N_NODES 100000
#define D_FEAT 128
#define N_CLASSES 32
#define BSHIFT 8
#define NB 391            // ceil(100000/256) dst buckets of 256 nodes
#define EPB 4096          // edges per partition block
#define CAPB 5120         // per-bucket region capacity (mean 4092 + >8 sigma)
#define GCAP 1536         // per-quarter sorted capacity (mean 1023 + >8 sigma)
#define GSTRIDE 16        // gcount padded to one counter per 64B line

typedef __attribute__((ext_vector_type(8))) short short8;
typedef __attribute__((ext_vector_type(4))) float f32x4;

__device__ __forceinline__ unsigned short f2bf(float f) {
  unsigned u = __float_as_uint(f);
  u += 0x7fffu + ((u >> 16) & 1);   // round-to-nearest-even
  return (unsigned short)(u >> 16);
}

// pack two f32 -> two bf16 (RNE) in one instruction
__device__ __forceinline__ unsigned cvtpk(float lo, float hi) {
  unsigned r;
  asm("v_cvt_pk_bf16_f32 %0, %1, %2" : "=v"(r) : "v"(lo), "v"(hi));
  return r;
}
__device__ __forceinline__ float bflo(unsigned v) { return __uint_as_float(v << 16); }
__device__ __forceinline__ float bfhi(unsigned v) { return __uint_as_float(v & 0xFFFF0000u); }

// ---------- prep: W -> bf16 table + zero padded bucket counters ----------
__global__ __launch_bounds__(256) void gin_prep(const float* __restrict__ W,
                                                unsigned short* __restrict__ Wb,
                                                int* __restrict__ gcount) {
  int i = blockIdx.x * 256 + threadIdx.x;
  if (i < D_FEAT * N_CLASSES) Wb[i] = f2bf(W[i]);
  if (i < NB * GSTRIDE) gcount[i] = 0;
}

// ---------- partition: 391 blocks (r9-proven, now its own dispatch) ----------
__global__ __launch_bounds__(256) void gin_part(
    const int* __restrict__ src, const int* __restrict__ dst,
    int* __restrict__ gcount, unsigned* __restrict__ bucketed, int E) {
  __shared__ int cnt[NB];
  __shared__ int cur[NB];
  __shared__ int gbase[NB];
  int tid = threadIdx.x;
  int blk = blockIdx.x;
  for (int i = tid; i < NB; i += 256) {
    cnt[i] = 0;
    cur[i] = 0;
  }
  __syncthreads();
  int base = blk * EPB;
  bool full = (base + EPB <= E);

  int dv[16];
  unsigned sv[16];
  if (full) {
#pragma unroll
    for (int k = 0; k < 16; ++k) dv[k] = dst[base + k * 256 + tid];
#pragma unroll
    for (int k = 0; k < 16; ++k) sv[k] = (unsigned)src[base + k * 256 + tid];
  } else {
#pragma unroll
    for (int k = 0; k < 16; ++k) {
      int e = base + k * 256 + tid;
      dv[k] = (e < E) ? dst[e] : -1;
      sv[k] = (e < E) ? (unsigned)src[e] : 0u;
    }
  }
#pragma unroll
  for (int k = 0; k < 16; ++k)
    if (dv[k] >= 0) atomicAdd(&cnt[dv[k] >> BSHIFT], 1);
  __syncthreads();

  for (int i = tid; i < NB; i += 256) {
    int c = cnt[i];
    gbase[i] = c ? atomicAdd(&gcount[i * GSTRIDE], c) : 0;
  }
  __syncthreads();

#pragma unroll
  for (int k = 0; k < 16; ++k) {
    if (dv[k] >= 0) {
      int b = dv[k] >> BSHIFT;
      int r = atomicAdd(&cur[b], 1);
      int ga = gbase[b] + r;
      if (ga < CAPB)
        bucketed[(size_t)b * CAPB + ga] = sv[k] | ((unsigned)(dv[k] & 255) << 17);
    }
  }
}

// ---------- projection: 2 tiles/wave, FORCED load batch ----------
// All 16 x-float4 loads issue before any cvt: sched_barrier(0) pins the
// schedule (rule #18's tool). 16 independent 16B loads in flight per wave vs
// r10/r11's compiler-serialized ~2 (VGPR 40 proved the fold). VGPR rises to
// ~90-110 -> still >= 18 waves/SIMD-group budget. Verify via VGPR_Count >= 90.
__global__ __launch_bounds__(256) void gin_proj(
    const float* __restrict__ x, const unsigned short* __restrict__ Wb,
    float* __restrict__ y, unsigned short* __restrict__ yh) {
  int tid = threadIdx.x;
  int wave = tid >> 6, lane = tid & 63;
  int node_base = blockIdx.x * 128 + wave * 32;   // 100000 = 781*128+32: partial block tail handled by wave guard
  if (node_base + 31 >= N_NODES && node_base >= N_NODES) return;
  if (node_base >= N_NODES) return;
  int m = lane & 15, quad = lane >> 4;

  // B fragments (L2-hot 8 KB table, shared by both tiles)
  short8 bfrag[2][4];
#pragma unroll
  for (int cb = 0; cb < 2; ++cb) {
    const unsigned short* wr = Wb + (cb * 16 + m) * D_FEAT + quad * 8;
#pragma unroll
    for (int ks = 0; ks < 4; ++ks)
      bfrag[cb][ks] = *(const short8*)(wr + ks * 32);
  }

  // issue ALL x loads for both tiles (16 x 16B independent)
  const float* xrA = x + (size_t)(node_base + m) * D_FEAT + quad * 8;
  const float* xrB = xrA + 16 * D_FEAT;
  float4 fA0[4], fA1[4], fB0[4], fB1[4];
#pragma unroll
  for (int ks = 0; ks < 4; ++ks) {
    fA0[ks] = *(const float4*)(xrA + ks * 32);
    fA1[ks] = *(const float4*)(xrA + ks * 32 + 4);
    fB0[ks] = *(const float4*)(xrB + ks * 32);
    fB1[ks] = *(const float4*)(xrB + ks * 32 + 4);
  }
  __builtin_amdgcn_sched_barrier(0);   // nothing crosses: all 16 loads issued first

  short8 afragA[4], afragB[4];
#pragma unroll
  for (int ks = 0; ks < 4; ++ks) {
    union { uint4 u; short8 s; } ua, ub;
    ua.u.x = cvtpk(fA0[ks].x, fA0[ks].y);
    ua.u.y = cvtpk(fA0[ks].z, fA0[ks].w);
    ua.u.z = cvtpk(fA1[ks].x, fA1[ks].y);
    ua.u.w = cvtpk(fA1[ks].z, fA1[ks].w);
    afragA[ks] = ua.s;
    ub.u.x = cvtpk(fB0[ks].x, fB0[ks].y);
    ub.u.y = cvtpk(fB0[ks].z, fB0[ks].w);
    ub.u.z = cvtpk(fB1[ks].x, fB1[ks].y);
    ub.u.w = cvtpk(fB1[ks].z, fB1[ks].w);
    afragB[ks] = ub.s;
  }

  f32x4 accA0 = {0.f, 0.f, 0.f, 0.f};
  f32x4 accA1 = {0.f, 0.f, 0.f, 0.f};
  f32x4 accB0 = {0.f, 0.f, 0.f, 0.f};
  f32x4 accB1 = {0.f, 0.f, 0.f, 0.f};
#pragma unroll
  for (int ks = 0; ks < 4; ++ks) {
    accA0 = __builtin_amdgcn_mfma_f32_16x16x32_bf16(afragA[ks], bfrag[0][ks], accA0, 0, 0, 0);
    accB0 = __builtin_amdgcn_mfma_f32_16x16x32_bf16(afragB[ks], bfrag[0][ks], accB0, 0, 0, 0);
    accA1 = __builtin_amdgcn_mfma_f32_16x16x32_bf16(afragA[ks], bfrag[1][ks], accA1, 0, 0, 0);
    accB1 = __builtin_amdgcn_mfma_f32_16x16x32_bf16(afragB[ks], bfrag[1][ks], accB1, 0, 0, 0);
  }

#pragma unroll
  for (int r = 0; r < 4; ++r) {
    int nodeA = node_base + quad * 4 + r;
    y[(size_t)nodeA * N_CLASSES + m] = accA0[r];
    y[(size_t)nodeA * N_CLASSES + 16 + m] = accA1[r];
    unsigned pkA = cvtpk(accA0[r], accA1[r]);
    yh[(size_t)nodeA * N_CLASSES + m] = (unsigned short)(pkA & 0xFFFFu);
    yh[(size_t)nodeA * N_CLASSES + 16 + m] = (unsigned short)(pkA >> 16);
    int nodeB = nodeA + 16;
    y[(size_t)nodeB * N_CLASSES + m] = accB0[r];
    y[(size_t)nodeB * N_CLASSES + 16 + m] = accB1[r];
    unsigned pkB = cvtpk(accB0[r], accB1[r]);
    yh[(size_t)nodeB * N_CLASSES + m] = (unsigned short)(pkB & 0xFFFFu);
    yh[(size_t)nodeB * N_CLASSES + 16 + m] = (unsigned short)(pkB >> 16);
  }
}

// ---------- gather: 4 blocks/bucket; one global pass (stage+count), LDS ----------
// counting-scatter, then 8-threads-per-node accumulation from bf16 yh.
__global__ __launch_bounds__(512) void gin_gather_s(
    const int* __restrict__ gcount, const unsigned* __restrict__ bucketed,
    const float* __restrict__ y, const unsigned short* __restrict__ yh,
    const float* __restrict__ bias, float* __restrict__ out) {
  __shared__ unsigned stage[CAPB];   // 20 KB
  __shared__ unsigned sorted[GCAP];  // 6 KB
  __shared__ int cnt[64];
  __shared__ int off[65];
  __shared__ int cur[64];
  int tid = threadIdx.x;
  int bk = blockIdx.x >> 2;
  int qq = blockIdx.x & 3;
  int len = gcount[bk * GSTRIDE];
  if (len > CAPB) len = CAPB;
  const unsigned* bb = bucketed + (size_t)bk * CAPB;
  if (tid < 64) cnt[tid] = 0;
  __syncthreads();
  for (int i = tid; i < len; i += 512) {
    unsigned p = bb[i];
    stage[i] = p;
    int n8 = (int)((p >> 17) & 255u);
    if ((n8 >> 6) == qq) atomicAdd(&cnt[n8 & 63], 1);
  }
  __syncthreads();
  if (tid == 0) off[0] = 0;
  if (tid < 64) off[tid + 1] = cnt[tid];
  __syncthreads();
  for (int o = 1; o < 64; o <<= 1) {
    int v = (tid < 64 && tid >= o) ? off[tid + 1 - o] : 0;
    __syncthreads();
    if (tid < 64) off[tid + 1] += v;
    __syncthreads();
  }
  if (tid < 64) cur[tid] = off[tid];
  __syncthreads();
  for (int i = tid; i < len; i += 512) {
    unsigned p = stage[i];
    int n8 = (int)((p >> 17) & 255u);
    if ((n8 >> 6) == qq) {
      int pos = atomicAdd(&cur[n8 & 63], 1);
      if (pos < GCAP) sorted[pos] = p;
    }
  }
  __syncthreads();
  int nl = tid >> 3;                 // node-in-quarter 0..63
  int q = tid & 7;
  int es = off[nl], ee = off[nl + 1];
  if (ee > GCAP) ee = GCAP;
  if (es > ee) es = ee;
  int node = (bk << 8) + (qq << 6) + nl;
  if (node >= N_NODES) return;
  const float4* y4 = (const float4*)y;
  const unsigned* yh2 = (const unsigned*)yh;   // row stride 16 uints
  float4 bq = ((const float4*)bias)[q];
  float4 self = y4[(size_t)node * 8 + q];
  float4 acc;
  acc.x = self.x + bq.x;
  acc.y = self.y + bq.y;
  acc.z = self.z + bq.z;
  acc.w = self.w + bq.w;
  int j = es;
  for (; j + 4 <= ee; j += 4) {
    unsigned s0 = sorted[j] & 0x1FFFF, s1 = sorted[j + 1] & 0x1FFFF;
    unsigned s2 = sorted[j + 2] & 0x1FFFF, s3 = sorted[j + 3] & 0x1FFFF;
    uint2 v0 = *(const uint2*)(yh2 + (size_t)s0 * 16 + q * 2);
    uint2 v1 = *(const uint2*)(yh2 + (size_t)s1 * 16 + q * 2);
    uint2 v2 = *(const uint2*)(yh2 + (size_t)s2 * 16 + q * 2);
    uint2 v3 = *(const uint2*)(yh2 + (size_t)s3 * 16 + q * 2);
    acc.x += bflo(v0.x) + bflo(v1.x) + bflo(v2.x) + bflo(v3.x);
    acc.y += bfhi(v0.x) + bfhi(v1.x) + bfhi(v2.x) + bfhi(v3.x);
    acc.z += bflo(v0.y) + bflo(v1.y) + bflo(v2.y) + bflo(v3.y);
    acc.w += bfhi(v0.y) + bfhi(v1.y) + bfhi(v2.y) + bfhi(v3.y);
  }
  for (; j < ee; ++j) {
    unsigned s = sorted[j] & 0x1FFFF;
    uint2 v = *(const uint2*)(yh2 + (size_t)s * 16 + q * 2);
    acc.x += bflo(v.x);
    acc.y += bfhi(v.x);
    acc.z += bflo(v.y);
    acc.w += bfhi(v.y);
  }
  ((float4*)out)[(size_t)node * 8 + q] = acc;
}

// ---------- exact fallback: bias init + atomic scatter (f32 y) ----------
__global__ __launch_bounds__(256) void gin_bias_init(
    const float* __restrict__ y, const float* __restrict__ b,
    float* __restrict__ out) {
  int gid = blockIdx.x * 256 + threadIdx.x;
  if (gid < N_NODES * N_CLASSES) out[gid] = y[gid] + b[gid & 31];
}
__global__ __launch_bounds__(256) void gin_scatter_fb(
    const int* __restrict__ src, const int* __restrict__ dst,
    const float* __restrict__ y, float* __restrict__ out, int n_edges) {
  long long gid = (long long)blockIdx.x * 256 + threadIdx.x;
  int e = (int)(gid >> 5);
  int c = (int)(gid & 31);
  if (e >= n_edges) return;
  atomicAdd(&out[(size_t)dst[e] * N_CLASSES + c],
            y[(size_t)src[e] * N_CLASSES + c]);
}

extern "C" void kernel_launch(void* const* d_in, const int* in_sizes, int n_in,
                              void* d_out, int out_size, void* d_ws, size_t ws_size,
                              hipStream_t stream) {
  const float* x = (const float*)d_in[0];
  const int* edge_index = (const int*)d_in[1];
  const float* W = (const float*)d_in[2];
  const float* b = (const float*)d_in[3];
  float* out = (float*)d_out;

  int E = in_sizes[1] / 2;
  const int* src = edge_index;
  const int* dst = edge_index + E;

  int GBr = (E + EPB - 1) / EPB;       // 391 for E=1.6M
  int pblocks = (N_NODES + 127) / 128; // 782 projection blocks (128 nodes each)

  char* ws = (char*)d_ws;
  size_t sz_y = (size_t)N_NODES * N_CLASSES * 4;                    // 12.8 MB
  size_t sz_yh = (((size_t)N_NODES * N_CLASSES * 2) + 15) & ~15ull; // 6.4 MB
  size_t sz_wb = (D_FEAT * N_CLASSES * 2 + 15) & ~15ull;            // 8 KB bf16 W
  size_t sz_bucketed = (((size_t)NB * CAPB * 4) + 15) & ~15ull;     // 8.0 MB
  size_t sz_gcnt = ((size_t)NB * GSTRIDE * 4 + 15) & ~15ull;        // 25 KB padded

  float* y = (float*)ws;
  unsigned short* yh = (unsigned short*)(ws + sz_y);
  unsigned short* Wb = (unsigned short*)(ws + sz_y + sz_yh);
  unsigned* bucketed = (unsigned*)(ws + sz_y + sz_yh + sz_wb);
  int* gcount = (int*)(ws + sz_y + sz_yh + sz_wb + sz_bucketed);
  size_t need = sz_y + sz_yh + sz_wb + sz_bucketed + sz_gcnt;

  // capacity guard: CAPB=5120 covers mean E/391 + 8 sigma up to E ~ 1.75M
  bool dense = E > 1750000;

  if (ws_size < need || dense) {
    gin_prep<<<25, 256, 0, stream>>>(W, Wb, (int*)ws);  // scratch; y overwritten next
    gin_proj<<<pblocks, 256, 0, stream>>>(x, Wb, y, yh);
    gin_bias_init<<<(N_NODES * N_CLASSES + 255) / 256, 256, 0, stream>>>(y, b, out);
    long long t2 = (long long)E * N_CLASSES;
    gin_scatter_fb<<<(int)((t2 + 255) / 256), 256, 0, stream>>>(src, dst, y, out, E);
    return;
  }

  gin_prep<<<25, 256, 0, stream>>>(W, Wb, gcount);
  gin_part<<<GBr, 256, 0, stream>>>(src, dst, gcount, bucketed, E);
  gin_proj<<<pblocks, 256, 0, stream>>>(x, Wb, y, yh);
  gin_gather_s<<<NB * 4, 512, 0, stream>>>(gcount, bucketed, y, yh, b, out);
}

// Round 13
// 150.374 us; speedup vs baseline: 1.0378x; 1.0378x over previous
//
#include <hip/hip_runtime.h>

#define N_NODES 100000
#define D_FEAT 128
#define N_CLASSES 32
#define BSHIFT 8
#define NB 391            // ceil(100000/256) dst buckets of 256 nodes
#define EPB 4096          // edges per partition block
#define CAPB 5120         // per-bucket region capacity (mean 4092 + >8 sigma)
#define GCAP 1536         // per-quarter sorted capacity (mean 1023 + >8 sigma)

typedef __attribute__((ext_vector_type(8))) short short8;
typedef __attribute__((ext_vector_type(4))) float f32x4;

__device__ __forceinline__ unsigned short f2bf(float f) {
  unsigned u = __float_as_uint(f);
  u += 0x7fffu + ((u >> 16) & 1);   // round-to-nearest-even
  return (unsigned short)(u >> 16);
}

// pack two f32 -> two bf16 (RNE) in one instruction
__device__ __forceinline__ unsigned cvtpk(float lo, float hi) {
  unsigned r;
  asm("v_cvt_pk_bf16_f32 %0, %1, %2" : "=v"(r) : "v"(lo), "v"(hi));
  return r;
}
__device__ __forceinline__ float bflo(unsigned v) { return __uint_as_float(v << 16); }
__device__ __forceinline__ float bfhi(unsigned v) { return __uint_as_float(v & 0xFFFF0000u); }

// ---------- prep: W -> bf16 table + zero bucket counters ----------
__global__ __launch_bounds__(256) void gin_prep(const float* __restrict__ W,
                                                unsigned short* __restrict__ Wb,
                                                int* __restrict__ gcount) {
  int i = blockIdx.x * 256 + threadIdx.x;
  if (i < D_FEAT * N_CLASSES) Wb[i] = f2bf(W[i]);
  if (i < NB) gcount[i] = 0;
}

// ---------- fused mid: blocks [0,GBr) partition edges, rest MFMA projection ----------
// r8 configuration — session-best measured (150.8 us total).
// Partition: edges read ONCE into registers -> LDS histogram -> reserve global
// per-bucket ranges (one atomicAdd per (block,bucket); within-bucket order
// irrelevant, so no scan) -> DIRECT scattered store. Runs of ~10.5 consecutive
// slots per (block,bucket) are written by one block => ~2x line amp. LDS 4.7 KB.
// Projection: wave = 16 nodes x 32 classes; writes f32 y (exact self-term) AND
// bf16 yh (gather aggregate table, halves gather's random-read bytes).
__global__ __launch_bounds__(256) void gin_mid(
    const float* __restrict__ x, const unsigned short* __restrict__ Wb,
    float* __restrict__ y, unsigned short* __restrict__ yh,
    const int* __restrict__ src, const int* __restrict__ dst,
    int* __restrict__ gcount, unsigned* __restrict__ bucketed,
    int E, int GBr) {
  __shared__ int cnt[NB];
  __shared__ int cur[NB];
  __shared__ int gbase[NB];
  int tid = threadIdx.x;

  if ((int)blockIdx.x >= GBr) {
    // ================= projection path =================
    int pb = blockIdx.x - GBr;
    int wave = tid >> 6, lane = tid & 63;
    int node_base = pb * 64 + wave * 16;
    if (node_base >= N_NODES) return;
    int m = lane & 15, quad = lane >> 4;

    short8 bfrag[2][4];
#pragma unroll
    for (int cb = 0; cb < 2; ++cb) {
      const unsigned short* wr = Wb + (cb * 16 + m) * D_FEAT + quad * 8;
#pragma unroll
      for (int ks = 0; ks < 4; ++ks)
        bfrag[cb][ks] = *(const short8*)(wr + ks * 32);
    }

    const float* xr = x + (size_t)(node_base + m) * D_FEAT + quad * 8;
    short8 afrag[4];
#pragma unroll
    for (int ks = 0; ks < 4; ++ks) {
      float4 f0 = *(const float4*)(xr + ks * 32);
      float4 f1 = *(const float4*)(xr + ks * 32 + 4);
      union { uint4 u; short8 s; } au;
      au.u.x = cvtpk(f0.x, f0.y);
      au.u.y = cvtpk(f0.z, f0.w);
      au.u.z = cvtpk(f1.x, f1.y);
      au.u.w = cvtpk(f1.z, f1.w);
      afrag[ks] = au.s;
    }

    f32x4 acc0 = {0.f, 0.f, 0.f, 0.f};
    f32x4 acc1 = {0.f, 0.f, 0.f, 0.f};
#pragma unroll
    for (int ks = 0; ks < 4; ++ks) {
      acc0 = __builtin_amdgcn_mfma_f32_16x16x32_bf16(afrag[ks], bfrag[0][ks], acc0, 0, 0, 0);
      acc1 = __builtin_amdgcn_mfma_f32_16x16x32_bf16(afrag[ks], bfrag[1][ks], acc1, 0, 0, 0);
    }

#pragma unroll
    for (int r = 0; r < 4; ++r) {
      int node = node_base + quad * 4 + r;
      y[(size_t)node * N_CLASSES + m] = acc0[r];
      y[(size_t)node * N_CLASSES + 16 + m] = acc1[r];
      unsigned pk = cvtpk(acc0[r], acc1[r]);   // [bf16 col m | bf16 col m+16]
      yh[(size_t)node * N_CLASSES + m] = (unsigned short)(pk & 0xFFFFu);
      yh[(size_t)node * N_CLASSES + 16 + m] = (unsigned short)(pk >> 16);
    }
    return;
  }

  // ================= partition path (4.7 KB LDS) =================
  int blk = blockIdx.x;
  for (int i = tid; i < NB; i += 256) {
    cnt[i] = 0;
    cur[i] = 0;
  }
  __syncthreads();
  int base = blk * EPB;
  bool full = (base + EPB <= E);

  int dv[16];
  unsigned sv[16];
  if (full) {
#pragma unroll
    for (int k = 0; k < 16; ++k) dv[k] = dst[base + k * 256 + tid];
#pragma unroll
    for (int k = 0; k < 16; ++k) sv[k] = (unsigned)src[base + k * 256 + tid];
  } else {
#pragma unroll
    for (int k = 0; k < 16; ++k) {
      int e = base + k * 256 + tid;
      dv[k] = (e < E) ? dst[e] : -1;
      sv[k] = (e < E) ? (unsigned)src[e] : 0u;
    }
  }
#pragma unroll
  for (int k = 0; k < 16; ++k)
    if (dv[k] >= 0) atomicAdd(&cnt[dv[k] >> BSHIFT], 1);
  __syncthreads();

  for (int i = tid; i < NB; i += 256) {
    int c = cnt[i];
    gbase[i] = c ? atomicAdd(&gcount[i], c) : 0;
  }
  __syncthreads();

#pragma unroll
  for (int k = 0; k < 16; ++k) {
    if (dv[k] >= 0) {
      int b = dv[k] >> BSHIFT;
      int r = atomicAdd(&cur[b], 1);
      int ga = gbase[b] + r;
      if (ga < CAPB)
        bucketed[(size_t)b * CAPB + ga] = sv[k] | ((unsigned)(dv[k] & 255) << 17);
    }
  }
}

// ---------- gather: 4 blocks/bucket; one global pass (stage+count), LDS ----------
// counting-scatter, then 8-threads-per-node accumulation from bf16 yh (uint2 =
// 8 B per neighbor per thread; the 8 q-threads cover the 64 B row contiguously).
// Self-term from f32 y. out = agg + y + b.
__global__ __launch_bounds__(512) void gin_gather_s(
    const int* __restrict__ gcount, const unsigned* __restrict__ bucketed,
    const float* __restrict__ y, const unsigned short* __restrict__ yh,
    const float* __restrict__ bias, float* __restrict__ out) {
  __shared__ unsigned stage[CAPB];   // 20 KB
  __shared__ unsigned sorted[GCAP];  // 6 KB
  __shared__ int cnt[64];
  __shared__ int off[65];
  __shared__ int cur[64];
  int tid = threadIdx.x;
  int bk = blockIdx.x >> 2;
  int qq = blockIdx.x & 3;
  int len = gcount[bk];
  if (len > CAPB) len = CAPB;
  const unsigned* bb = bucketed + (size_t)bk * CAPB;
  if (tid < 64) cnt[tid] = 0;
  __syncthreads();
  // single global pass: stage + count own quarter
  for (int i = tid; i < len; i += 512) {
    unsigned p = bb[i];
    stage[i] = p;
    int n8 = (int)((p >> 17) & 255u);
    if ((n8 >> 6) == qq) atomicAdd(&cnt[n8 & 63], 1);
  }
  __syncthreads();
  if (tid == 0) off[0] = 0;
  if (tid < 64) off[tid + 1] = cnt[tid];
  __syncthreads();
  for (int o = 1; o < 64; o <<= 1) {
    int v = (tid < 64 && tid >= o) ? off[tid + 1 - o] : 0;
    __syncthreads();
    if (tid < 64) off[tid + 1] += v;
    __syncthreads();
  }
  if (tid < 64) cur[tid] = off[tid];
  __syncthreads();
  // LDS -> LDS counting-scatter (no global re-read)
  for (int i = tid; i < len; i += 512) {
    unsigned p = stage[i];
    int n8 = (int)((p >> 17) & 255u);
    if ((n8 >> 6) == qq) {
      int pos = atomicAdd(&cur[n8 & 63], 1);
      if (pos < GCAP) sorted[pos] = p;
    }
  }
  __syncthreads();
  // accumulate: 8 threads per node, thread q owns classes 4q..4q+3
  int nl = tid >> 3;                 // node-in-quarter 0..63
  int q = tid & 7;
  int es = off[nl], ee = off[nl + 1];
  if (ee > GCAP) ee = GCAP;
  if (es > ee) es = ee;
  int node = (bk << 8) + (qq << 6) + nl;
  if (node >= N_NODES) return;
  const float4* y4 = (const float4*)y;
  const unsigned* yh2 = (const unsigned*)yh;   // row stride 16 uints
  float4 bq = ((const float4*)bias)[q];
  float4 self = y4[(size_t)node * 8 + q];
  float4 acc;
  acc.x = self.x + bq.x;
  acc.y = self.y + bq.y;
  acc.z = self.z + bq.z;
  acc.w = self.w + bq.w;
  int j = es;
  for (; j + 4 <= ee; j += 4) {
    unsigned s0 = sorted[j] & 0x1FFFF, s1 = sorted[j + 1] & 0x1FFFF;
    unsigned s2 = sorted[j + 2] & 0x1FFFF, s3 = sorted[j + 3] & 0x1FFFF;
    uint2 v0 = *(const uint2*)(yh2 + (size_t)s0 * 16 + q * 2);
    uint2 v1 = *(const uint2*)(yh2 + (size_t)s1 * 16 + q * 2);
    uint2 v2 = *(const uint2*)(yh2 + (size_t)s2 * 16 + q * 2);
    uint2 v3 = *(const uint2*)(yh2 + (size_t)s3 * 16 + q * 2);
    acc.x += bflo(v0.x) + bflo(v1.x) + bflo(v2.x) + bflo(v3.x);
    acc.y += bfhi(v0.x) + bfhi(v1.x) + bfhi(v2.x) + bfhi(v3.x);
    acc.z += bflo(v0.y) + bflo(v1.y) + bflo(v2.y) + bflo(v3.y);
    acc.w += bfhi(v0.y) + bfhi(v1.y) + bfhi(v2.y) + bfhi(v3.y);
  }
  for (; j < ee; ++j) {
    unsigned s = sorted[j] & 0x1FFFF;
    uint2 v = *(const uint2*)(yh2 + (size_t)s * 16 + q * 2);
    acc.x += bflo(v.x);
    acc.y += bfhi(v.x);
    acc.z += bflo(v.y);
    acc.w += bfhi(v.y);
  }
  ((float4*)out)[(size_t)node * 8 + q] = acc;
}

// ---------- exact fallback: bias init + atomic scatter (f32 y) ----------
__global__ __launch_bounds__(256) void gin_bias_init(
    const float* __restrict__ y, const float* __restrict__ b,
    float* __restrict__ out) {
  int gid = blockIdx.x * 256 + threadIdx.x;
  if (gid < N_NODES * N_CLASSES) out[gid] = y[gid] + b[gid & 31];
}
__global__ __launch_bounds__(256) void gin_scatter_fb(
    const int* __restrict__ src, const int* __restrict__ dst,
    const float* __restrict__ y, float* __restrict__ out, int n_edges) {
  long long gid = (long long)blockIdx.x * 256 + threadIdx.x;
  int e = (int)(gid >> 5);
  int c = (int)(gid & 31);
  if (e >= n_edges) return;
  atomicAdd(&out[(size_t)dst[e] * N_CLASSES + c],
            y[(size_t)src[e] * N_CLASSES + c]);
}

extern "C" void kernel_launch(void* const* d_in, const int* in_sizes, int n_in,
                              void* d_out, int out_size, void* d_ws, size_t ws_size,
                              hipStream_t stream) {
  const float* x = (const float*)d_in[0];
  const int* edge_index = (const int*)d_in[1];
  const float* W = (const float*)d_in[2];
  const float* b = (const float*)d_in[3];
  float* out = (float*)d_out;

  int E = in_sizes[1] / 2;
  const int* src = edge_index;
  const int* dst = edge_index + E;

  int GBr = (E + EPB - 1) / EPB;      // 391 for E=1.6M
  int pblocks = (N_NODES + 63) / 64;  // 1563 projection blocks

  char* ws = (char*)d_ws;
  size_t sz_y = (size_t)N_NODES * N_CLASSES * 4;                    // 12.8 MB
  size_t sz_yh = (((size_t)N_NODES * N_CLASSES * 2) + 15) & ~15ull; // 6.4 MB
  size_t sz_wb = (D_FEAT * N_CLASSES * 2 + 15) & ~15ull;            // 8 KB bf16 W
  size_t sz_bucketed = (((size_t)NB * CAPB * 4) + 15) & ~15ull;     // 8.0 MB
  size_t sz_gcnt = ((size_t)NB * 4 + 15) & ~15ull;

  float* y = (float*)ws;
  unsigned short* yh = (unsigned short*)(ws + sz_y);
  unsigned short* Wb = (unsigned short*)(ws + sz_y + sz_yh);
  unsigned* bucketed = (unsigned*)(ws + sz_y + sz_yh + sz_wb);
  int* gcount = (int*)(ws + sz_y + sz_yh + sz_wb + sz_bucketed);
  size_t need = sz_y + sz_yh + sz_wb + sz_bucketed + sz_gcnt;

  // capacity guard: CAPB=5120 covers mean E/391 + 8 sigma up to E ~ 1.75M
  bool dense = E > 1750000;

  if (ws_size < need || dense) {
    gin_prep<<<16, 256, 0, stream>>>(W, Wb, (int*)ws);  // scratch; y overwritten next
    gin_mid<<<pblocks, 256, 0, stream>>>(x, Wb, y, yh, src, dst,
                                         (int*)ws, (unsigned*)ws, E, 0);
    gin_bias_init<<<(N_NODES * N_CLASSES + 255) / 256, 256, 0, stream>>>(y, b, out);
    long long t2 = (long long)E * N_CLASSES;
    gin_scatter_fb<<<(int)((t2 + 255) / 256), 256, 0, stream>>>(src, dst, y, out, E);
    return;
  }

  gin_prep<<<16, 256, 0, stream>>>(W, Wb, gcount);
  gin_mid<<<GBr + pblocks, 256, 0, stream>>>(x, Wb, y, yh, src, dst,
                                             gcount, bucketed, E, GBr);
  gin_gather_s<<<NB * 4, 512, 0, stream>>>(gcount, bucketed, y, yh, b, out);
}